// Round 5
// baseline (599.557 us; speedup 1.0000x reference)
//
#include <hip/hip_runtime.h>
#include <hip/hip_bf16.h>
#include <stdint.h>

#define TLEN 2048
#define CDIM 2048
#define BDIM 2
#define HDIM 16
#define DHEAD 128
// Q/K packed at stride 2*CDIM; V goes to a separate transposed buffer.
#define QROW ((size_t)(2 * CDIM))

typedef __bf16 bf16x8 __attribute__((ext_vector_type(8)));
typedef float f32x4 __attribute__((ext_vector_type(4)));

__device__ __forceinline__ uint16_t f32_to_bf16(float f) {
    uint32_t u = __builtin_bit_cast(uint32_t, f);
    uint32_t r = (u + 0x7FFFu + ((u >> 16) & 1u)) >> 16;
    return (uint16_t)r;
}
__device__ __forceinline__ float bf16_to_f32(uint32_t h) {
    uint32_t u = h << 16;
    return __builtin_bit_cast(float, u);
}

// async global->LDS, 16B per lane. LDS dest = wave-uniform base + lane*16;
// global source address is per-lane (gather) — used for swizzled staging.
__device__ __forceinline__ void gload_lds16(const uint16_t* g, uint16_t* l) {
    __builtin_amdgcn_global_load_lds(
        (const __attribute__((address_space(1))) uint32_t*)g,
        (__attribute__((address_space(3))) uint32_t*)l, 16, 0, 0);
}

// ---------------- elementwise f32 -> bf16 ----------------
__global__ void cvt_f32_bf16(const float* __restrict__ in, uint16_t* __restrict__ out, int n) {
    int i = (blockIdx.x * blockDim.x + threadIdx.x) * 4;
    if (i + 3 < n) {
        float4 f = *reinterpret_cast<const float4*>(in + i);
        ushort4 o;
        o.x = f32_to_bf16(f.x);
        o.y = f32_to_bf16(f.y);
        o.z = f32_to_bf16(f.z);
        o.w = f32_to_bf16(f.w);
        *reinterpret_cast<ushort4*>(out + i) = o;
    }
}

// ---------------- transpose + cast: in [R][Cc] f32 -> out [Cc][R] bf16 ----------------
__global__ __launch_bounds__(256) void transpose_cvt(const float* __restrict__ in,
                                                     uint16_t* __restrict__ out,
                                                     int R, int Cc) {
    __shared__ uint16_t tile[64][65];
    int c0 = blockIdx.x * 64;
    int r0 = blockIdx.y * 64;
    int tc = threadIdx.x & 63;
    int t4 = threadIdx.x >> 6;  // 0..3
    for (int rr = t4; rr < 64; rr += 4) {
        tile[rr][tc] = f32_to_bf16(in[(size_t)(r0 + rr) * Cc + c0 + tc]);
    }
    __syncthreads();
    int wr = threadIdx.x & 63;
    for (int cc = t4; cc < 64; cc += 4) {
        out[(size_t)(c0 + cc) * R + r0 + wr] = tile[wr][cc];
    }
}

// ====== 256x256 bf16 MFMA GEMM: half-unit LDS ring + one-phase-ahead reads ======
// C[M][N] = A[M][K] * Bt[N][K]^T. 512 thr = 8 waves (2M x 4N); wave tile 128x64;
// BK=64; LDS ring of 4 half-unit slots per operand (even tiles slots 0/1, odd 2/3).
// ROUND-5 CHANGE: fragment ds_reads are issued ONE PHASE AHEAD of the MFMA
// cluster that consumes them, with counted lgkmcnt (4/8/0/12), so each phase's
// MFMA hides the next phase's LDS read latency. Rounds 1-4 showed per-tile time
// pinned at ~5000 cyc across staging-schedule and fetch changes; the exposed
// per-phase lgkmcnt(0) read latency is the remaining in-phase overhead vs the
// m201 reference (~3300 cyc/tile).
// Quadrant order Q1(0,0) Q2(0,2) Q3(4,2) Q4(4,0): af halves adjacent (aL,aH
// single-buffered); bf double-buffered with parity swap (b0/b1). Read schedule:
//   c1 top: bfH(t) -> BFH        | Q1 = aL x BFL   lgkm(4)
//   c2 top: afH(t) -> aH         | Q2 = aL x BFH   lgkm(8)
//   c3 top: stage B(t+2)         | Q3 = aH x BFH   lgkm(0)  (covered by c2 MFMA)
//   c4: vmcnt(4); stage A(t+2); BARRIER; read aL,bfL(t+1) (aL, BFH bufs);
//       lgkm(12) (no wait)       | Q4 = aH x BFL
// The t+1 reads sit AFTER c4's opening barrier: every wave has executed its
// vmcnt, so all waves' global_load_lds for t+1 slots have landed (vmcnt is
// per-wave; the barrier provides the cross-wave guarantee).
// XCD mapping: rectangular per-XCD tiling (round 4; FETCH 176->90 MB verified).
// LDS swizzle: 16B-block c' = c ^ (row&7) via pre-swizzled global source.
// MODE 0: f32 out. MODE 2: QKV split — Q/K cols -> packed bf16 [M][2*CDIM],
// V cols -> transposed bf16 Vt[(b*16+h)*128+d][t].

#define RD8(P, OFF) (*reinterpret_cast<const bf16x8*>((P) + (OFF)))

#define RDA(DST, P, MB)                                         \
    _Pragma("unroll") for (int mi = 0; mi < 4; mi++) {          \
        DST[mi][0] = RD8(P, rdAo + ((MB) + mi) * 1024 + kblk0); \
        DST[mi][1] = RD8(P, rdAo + ((MB) + mi) * 1024 + kblk1); \
    }

#define RDB(DST, P, NB)                                         \
    _Pragma("unroll") for (int ni = 0; ni < 2; ni++) {          \
        DST[ni][0] = RD8(P, rdBo + ((NB) + ni) * 1024 + kblk0); \
        DST[ni][1] = RD8(P, rdBo + ((NB) + ni) * 1024 + kblk1); \
    }

#define MFMA8(AF, BF, MB, NIB)                                                \
    _Pragma("unroll") for (int mi = 0; mi < 4; mi++)                          \
    _Pragma("unroll") for (int ni = 0; ni < 2; ni++) {                        \
        acc[(MB) + mi][(NIB) + ni] = __builtin_amdgcn_mfma_f32_16x16x32_bf16( \
            AF[mi][0], BF[ni][0], acc[(MB) + mi][(NIB) + ni], 0, 0, 0);       \
        acc[(MB) + mi][(NIB) + ni] = __builtin_amdgcn_mfma_f32_16x16x32_bf16( \
            AF[mi][1], BF[ni][1], acc[(MB) + mi][(NIB) + ni], 0, 0, 0);       \
    }

#define PHASE(LGN, AF, BF, MB, NIB)                           \
    __builtin_amdgcn_s_barrier();                             \
    asm volatile("s_waitcnt lgkmcnt(" #LGN ")" ::: "memory"); \
    __builtin_amdgcn_sched_barrier(0);                        \
    __builtin_amdgcn_s_setprio(1);                            \
    MFMA8(AF, BF, MB, NIB)                                    \
    __builtin_amdgcn_s_setprio(0);                            \
    __builtin_amdgcn_s_barrier();                             \
    __builtin_amdgcn_sched_barrier(0);

#define TILE(S, T, BFL, BFH)                                  \
    {                                                         \
        const int k0 = (T) * 64;                              \
        const uint16_t* pA = As + ((S) + wrow) * 8192;        \
        const uint16_t* pB = Bs + ((S) + bsel) * 8192;        \
        const uint16_t* pAn = As + (((S) ^ 2) + wrow) * 8192; \
        const uint16_t* pBn = Bs + (((S) ^ 2) + bsel) * 8192; \
        /* c1: issue bfH(t); MFMA Q1 */                       \
        RDB(BFH, pB, 2)                                       \
        PHASE(4, aL, BFL, 0, 0)                               \
        /* c2: issue afH(t); MFMA Q2 */                       \
        RDA(aH, pA, 4)                                        \
        PHASE(8, aL, BFH, 0, 2)                               \
        /* c3: stage B(t+2); MFMA Q3 */                       \
        if ((T) + 2 < nt) {                                   \
            stB((S), 0, k0 + 128);                            \
            stB((S), 1, k0 + 128);                            \
        }                                                     \
        PHASE(0, aH, BFH, 4, 2)                               \
        /* c4: vmcnt; stage A; barrier; read t+1; MFMA Q4 */  \
        if ((T) + 2 < nt) {                                   \
            asm volatile("s_waitcnt vmcnt(4)" ::: "memory");  \
            stA((S), 0, k0 + 128);                            \
            stA((S), 1, k0 + 128);                            \
        } else if ((T) + 1 < nt) {                            \
            asm volatile("s_waitcnt vmcnt(0)" ::: "memory");  \
        }                                                     \
        __builtin_amdgcn_s_barrier();                         \
        if ((T) + 1 < nt) {                                   \
            RDA(aL, pAn, 0)                                   \
            RDB(BFH, pBn, 0)                                  \
        }                                                     \
        asm volatile("s_waitcnt lgkmcnt(12)" ::: "memory");   \
        __builtin_amdgcn_sched_barrier(0);                    \
        __builtin_amdgcn_s_setprio(1);                        \
        MFMA8(aH, BFL, 4, 0)                                  \
        __builtin_amdgcn_s_setprio(0);                        \
        __builtin_amdgcn_s_barrier();                         \
        __builtin_amdgcn_sched_barrier(0);                    \
    }

template <int MODE>
__global__ __launch_bounds__(512, 2) void gemm_bf16_256(const uint16_t* __restrict__ A,
                                                        const uint16_t* __restrict__ Bt,
                                                        void* __restrict__ Cp,
                                                        uint16_t* __restrict__ vt,
                                                        int M, int N, int K, int xm) {
    __shared__ __align__(16) uint16_t lds[65536];  // 128 KiB
    uint16_t* const As = lds;          // 4 ring slots x 8192 elems (128 rows x 64 K)
    uint16_t* const Bs = lds + 32768;  // 4 ring slots

    const int tid = threadIdx.x;
    const int wave = tid >> 6;
    const int lane = tid & 63;
    const int l15 = lane & 15;
    const int quad = lane >> 4;
    const int wrow = wave >> 2;  // 0..1 -> A half
    const int wcol = wave & 3;   // 0..3
    const int bsel = wcol >> 1;  // B half

    // rectangular XCD mapping (bijective; requires xm|gm and (8/xm)|gn).
    const int gm = gridDim.y, gn = gridDim.x;
    const int flat = blockIdx.y * gn + blockIdx.x;
    const int xcd = flat & 7;
    const int j = flat >> 3;  // 0 .. gm*gn/8 - 1
    const int xn = 8 / xm;
    const int RM = gm / xm;  // rect height (m-blocks)
    const int RN = gn / xn;  // rect width (n-blocks)
    const int m_blk = (xcd / xn) * RM + (j % RM);
    const int n_blk = (xcd % xn) * RN + (j / RM);
    const int m0 = m_blk * 256;
    const int n0 = n_blk * 256;

    // staging: lane -> row (lane>>3) within 8-row slab, source 16B-block
    // (lane&7) ^ (lane>>3) so that LDS (r, c') holds global block c' ^ (r&7).
    const int srow = wave * 8 + (lane >> 3);
    const int scol = ((lane & 7) ^ (lane >> 3)) * 8;
    const uint16_t* Ag = A + (size_t)(m0 + srow) * K + scol;
    const uint16_t* Bg = Bt + (size_t)(n0 + srow) * K + scol;
    const int ldsoff = wave * 512;

    // frag-read constants within a half-unit (row&7 == l15&7 for all frag rows)
    const int rdAo = l15 * 64;
    const int rdBo = ((wcol & 1) * 64 + l15) * 64;
    const int kblk0 = (quad ^ (l15 & 7)) * 8;
    const int kblk1 = ((4 + quad) ^ (l15 & 7)) * 8;

    const int nt = K >> 6;
    f32x4 acc[8][4] = {};
    bf16x8 aL[4][2], aH[4][2], b0[2][2], b1[2][2];

    auto stA = [&](int sb, int h, int kk) {
        const uint16_t* s = Ag + (size_t)(h * 128) * K + kk;
        uint16_t* d = As + (sb + h) * 8192 + ldsoff;
        gload_lds16(s, d);
        gload_lds16(s + (size_t)64 * K, d + 4096);
    };
    auto stB = [&](int sb, int h, int kk) {
        const uint16_t* s = Bg + (size_t)(h * 128) * K + kk;
        uint16_t* d = Bs + (sb + h) * 8192 + ldsoff;
        gload_lds16(s, d);
        gload_lds16(s + (size_t)64 * K, d + 4096);
    };

    // prologue: tile 0 -> slots 0/1, tile 1 -> slots 2/3 (16 loads);
    // vmcnt(8) retires tile-0 units; barrier gives cross-wave visibility;
    // then pre-read tile-0 Q1 fragments (aL, bfL -> b0).
    stB(0, 0, 0);
    stB(0, 1, 0);
    stA(0, 0, 0);
    stA(0, 1, 0);
    stB(2, 0, 64);
    stB(2, 1, 64);
    stA(2, 0, 64);
    stA(2, 1, 64);
    asm volatile("s_waitcnt vmcnt(8)" ::: "memory");
    __builtin_amdgcn_s_barrier();
    __builtin_amdgcn_sched_barrier(0);
    RDA(aL, (As + wrow * 8192), 0)
    RDB(b0, (Bs + bsel * 8192), 0)

    for (int t = 0; t < nt; t += 2) {
        TILE(0, t, b0, b1)
        TILE(2, t + 1, b1, b0)
    }

    const bool vmode = (MODE == 2) && (n0 >= 2 * CDIM);  // block-uniform
#pragma unroll
    for (int mi = 0; mi < 8; mi++)
#pragma unroll
        for (int ni = 0; ni < 4; ni++) {
            if (vmode) {
                // V cols: write transposed into Vt[(b*16+h)*128+d][t].
                int col = n0 + wcol * 64 + ni * 16 + l15;
                int vcol = col - 2 * CDIM;
                int hh = vcol >> 7, d = vcol & 127;
                int rowm = m0 + wrow * 128 + mi * 16 + quad * 4;
                int bb = rowm >> 11, tt = rowm & 2047;
                uint32_t lo = (uint32_t)f32_to_bf16(acc[mi][ni][0]) |
                              ((uint32_t)f32_to_bf16(acc[mi][ni][1]) << 16);
                uint32_t hi = (uint32_t)f32_to_bf16(acc[mi][ni][2]) |
                              ((uint32_t)f32_to_bf16(acc[mi][ni][3]) << 16);
                *reinterpret_cast<uint2*>(
                    vt + ((size_t)((bb * HDIM + hh) * DHEAD + d)) * TLEN + tt) =
                    make_uint2(lo, hi);
            } else {
#pragma unroll
                for (int r = 0; r < 4; r++) {
                    int row = m0 + wrow * 128 + mi * 16 + quad * 4 + r;
                    int col = n0 + wcol * 64 + ni * 16 + l15;
                    float v = acc[mi][ni][r];
                    if (MODE == 2)
                        ((uint16_t*)Cp)[(size_t)row * (2 * CDIM) + col] = f32_to_bf16(v);
                    else if (MODE == 1)
                        ((uint16_t*)Cp)[(size_t)row * N + col] = f32_to_bf16(v);
                    else
                        ((float*)Cp)[(size_t)row * N + col] = v;
                }
            }
        }
}

// ---------------- MFMA flash attention v3 (QROW = 2*CDIM) ----------------
#define ATT_C1 0.12751743f
#define ATT_C2 17.3123405f

__global__ __launch_bounds__(256) void attn_mfma3(const uint16_t* __restrict__ qkv,
                                                  const uint16_t* __restrict__ vtg,
                                                  uint16_t* __restrict__ y) {
    __shared__ __align__(16) uint16_t Ks[64 * 128];    // swizzled: c' = c ^ (key&15)
    __shared__ __align__(16) uint16_t Vts[128 * 64];   // swizzled: c' = c ^ (d&7)
    __shared__ __align__(16) uint16_t Ps[4][32 * 72];  // per-wave P [q][key]

    const int tid = threadIdx.x;
    const int wave = tid >> 6;
    const int lane = tid & 63;
    const int l15 = lane & 15;
    const int quad = lane >> 4;
    const int h = blockIdx.y;
    const int b = blockIdx.z;
    const int qblk = (int)gridDim.x - 1 - (int)blockIdx.x;
    const int qbase = qblk * 128 + wave * 32;
    const int kmax = qbase + 31;

    const uint16_t* kg = qkv + (size_t)b * TLEN * QROW + CDIM + h * DHEAD;
    const uint16_t* vg = vtg + (size_t)(b * HDIM + h) * DHEAD * TLEN;
    uint16_t* PsW = Ps[wave];

    int koff[4], voff[4];
#pragma unroll
    for (int i = 0; i < 4; i++) {
        int Lb = (wave * 4 + i) * 64 + lane;
        int key = Lb >> 4;
        int ck = (Lb & 15) ^ (key & 15);
        koff[i] = key * (int)QROW + ck * 8;
        int d = Lb >> 3;
        int cv = (Lb & 7) ^ (d & 7);
        voff[i] = d * TLEN + cv * 8;
    }

    bf16x8 qfrag[2][4];
#pragma unroll
    for (int m = 0; m < 2; m++) {
        const uint16_t* qp =
            qkv + (size_t)(b * TLEN + qbase + m * 16 + l15) * QROW + h * DHEAD + quad * 8;
#pragma unroll
        for (int kc = 0; kc < 4; kc++)
            qfrag[m][kc] = *reinterpret_cast<const bf16x8*>(qp + kc * 32);
    }

    f32x4 oacc[2][8] = {};
    float psum[2] = {0.f, 0.f};

    const int diagT = qblk * 2 + (wave >> 1);
    const int ntiles = qblk * 2 + 2;

    for (int t = 0; t < ntiles; t++) {
        const int j0 = t * 64;
        if (t > 0) __syncthreads();
        {
            const uint16_t* kj = kg + (size_t)j0 * QROW;
            const uint16_t* vj = vg + j0;
#pragma unroll
            for (int i = 0; i < 4; i++) {
                gload_lds16(kj + koff[i], Ks + (wave * 4 + i) * 512);
                gload_lds16(vj + voff[i], Vts + (wave * 4 + i) * 512);
            }
        }
        __syncthreads();
        if (t > diagT) continue;

        const bool masked = (t == diagT);
        const int n0max = masked ? ((kmax - j0) >> 4) : 3;

        f32x4 st[4][2];
#pragma unroll
        for (int n0 = 0; n0 < 4; n0++) {
            if (masked && n0 > n0max) continue;
            bf16x8 kf[4];
#pragma unroll
            for (int kc = 0; kc < 4; kc++) {
                int cpr = (kc * 4 + quad) ^ l15;
                kf[kc] = *reinterpret_cast<const bf16x8*>(
                    Ks + (n0 * 16 + l15) * 128 + cpr * 8);
            }
#pragma unroll
            for (int m = 0; m < 2; m++) {
                f32x4 acc = {};
#pragma unroll
                for (int kc = 0; kc < 4; kc++)
                    acc = __builtin_amdgcn_mfma_f32_16x16x32_bf16(
                        kf[kc], qfrag[m][kc], acc, 0, 0, 0);
                st[n0][m] = acc;
            }
        }

#pragma unroll
        for (int n0 = 0; n0 < 4; n0++) {
            if (masked && n0 > n0max) continue;
#pragma unroll
            for (int m = 0; m < 2; m++) {
                uint32_t pk0, pk1;
                float pv[4];
#pragma unroll
                for (int r = 0; r < 4; r++) {
                    float p = exp2f(st[n0][m][r] * ATT_C1 - ATT_C2);
                    if (masked) {
                        int key = j0 + n0 * 16 + quad * 4 + r;
                        int q = qbase + m * 16 + l15;
                        if (key > q) p = 0.f;
                    }
                    uint32_t pb = f32_to_bf16(p);
                    pv[r] = bf16_to_f32(pb);
                    if (r == 0) pk0 = pb;
                    else if (r == 1) pk0 |= pb << 16;
                    else if (r == 2) pk1 = pb;
                    else pk1 |= pb << 16;
                }
                psum[m] += (pv[0] + pv[1]) + (pv[2] + pv[3]);
                *reinterpret_cast<uint2*>(PsW + (m * 16 + l15) * 72 + n0 * 16 + quad * 4) =
                    make_uint2(pk0, pk1);
            }
        }

        const int kcend = masked ? (((kmax - j0) >> 5) + 1) : 2;
#pragma unroll
        for (int kc = 0; kc < 2; kc++) {
            if (kc >= kcend) continue;
            bf16x8 pf[2];
#pragma unroll
            for (int m = 0; m < 2; m++)
                pf[m] = *reinterpret_cast<const bf16x8*>(
                    PsW + (m * 16 + l15) * 72 + kc * 32 + quad * 8);
#pragma unroll
            for (int n0 = 0; n0 < 8; n0++) {
                int cpr = (kc * 4 + quad) ^ (l15 & 7);
                bf16x8 vf = *reinterpret_cast<const bf16x8*>(
                    Vts + (n0 * 16 + l15) * 64 + cpr * 8);
#pragma unroll
                for (int m = 0; m < 2; m++)
                    oacc[m][n0] = __builtin_amdgcn_mfma_f32_16x16x32_bf16(
                        pf[m], vf, oacc[m][n0], 0, 0, 0);
            }
        }
    }

#pragma unroll
    for (int m = 0; m < 2; m++) {
        float s = psum[m];
        s += __shfl_xor(s, 16);
        s += __shfl_xor(s, 32);
        psum[m] = 1.0f / s;
    }
    uint16_t* ybase = y + (size_t)(b * TLEN + qbase) * CDIM + h * DHEAD;
#pragma unroll
    for (int m = 0; m < 2; m++)
#pragma unroll
        for (int r = 0; r < 4; r++) {
            float inv = __shfl(psum[m], quad * 4 + r);
#pragma unroll
            for (int n0 = 0; n0 < 8; n0++)
                ybase[(size_t)(m * 16 + quad * 4 + r) * CDIM + n0 * 16 + l15] =
                    f32_to_bf16(oacc[m][n0][r] * inv);
        }
}

extern "C" void kernel_launch(void* const* d_in, const int* in_sizes, int n_in,
                              void* d_out, int out_size, void* d_ws, size_t ws_size,
                              hipStream_t stream) {
    const float* x = (const float*)d_in[0];       // [2,2048,2048]
    const float* w_attn = (const float*)d_in[1];  // [2048, 6144]
    const float* w_proj = (const float*)d_in[2];  // [2048, 2048]
    float* out = (float*)d_out;                   // [2,2048,2048]

    const int M = BDIM * TLEN;  // 4096
    const int K = CDIM;         // 2048
    const int N3 = 3 * CDIM;    // 6144

    char* ws = (char*)d_ws;
    uint16_t* xb = (uint16_t*)(ws);              // 16 MB: x bf16
    uint16_t* waT = (uint16_t*)(ws + 16777216);  // 24 MB: w_attn^T bf16 [6144][2048]
    uint16_t* wpT = (uint16_t*)(ws + 41943040);  // 8 MB: w_proj^T bf16 [2048][2048]
    uint16_t* qkp = (uint16_t*)(ws + 50331648);  // 32 MB: packed Q/K bf16 [4096][4096]
    uint16_t* vtb = (uint16_t*)(ws + 83886080);  // 16 MB: Vt bf16 [(b*16+h)*128+d][2048]
    uint16_t* yb = (uint16_t*)(ws + 100663296);  // 16 MB: y bf16 [4096][2048]

    // 1. cast x to bf16
    cvt_f32_bf16<<<(M * K / 4 + 255) / 256, 256, 0, stream>>>(x, xb, M * K);
    // 2. transpose+cast weights
    transpose_cvt<<<dim3(N3 / 64, K / 64), 256, 0, stream>>>(w_attn, waT, K, N3);
    transpose_cvt<<<dim3(K / 64, K / 64), 256, 0, stream>>>(w_proj, wpT, K, K);
    // 3. qkv = x @ w_attn; Q/K cols -> qkp (stride 4096), V cols -> vtb transposed
    //    grid 24x16 -> XCD rect 8m x 6n (xm=2)
    gemm_bf16_256<2><<<dim3(N3 / 256, M / 256), 512, 0, stream>>>(xb, waT, (void*)qkp, vtb, M, N3, K, 2);
    // 4. attention -> y bf16 [4096][2048]
    attn_mfma3<<<dim3(TLEN / 128, HDIM, BDIM), 256, 0, stream>>>(qkp, vtb, yb);
    // 5. out = y @ w_proj   fp32 [4096][2048]
    //    grid 8x16 -> XCD rect 4m x 4n (xm=4)
    gemm_bf16_256<0><<<dim3(K / 256, M / 256), 512, 0, stream>>>(yb, wpT, (void*)out, nullptr, M, K, K, 4);
}

// Round 6
// 428.638 us; speedup vs baseline: 1.3987x; 1.3987x over previous
//
#include <hip/hip_runtime.h>
#include <hip/hip_bf16.h>
#include <stdint.h>

#define TLEN 2048
#define CDIM 2048
#define BDIM 2
#define HDIM 16
#define DHEAD 128
// Q/K packed at stride 2*CDIM; V goes to a separate transposed buffer.
#define QROW ((size_t)(2 * CDIM))

typedef __bf16 bf16x8 __attribute__((ext_vector_type(8)));
typedef float f32x4 __attribute__((ext_vector_type(4)));

__device__ __forceinline__ uint16_t f32_to_bf16(float f) {
    uint32_t u = __builtin_bit_cast(uint32_t, f);
    uint32_t r = (u + 0x7FFFu + ((u >> 16) & 1u)) >> 16;
    return (uint16_t)r;
}
__device__ __forceinline__ float bf16_to_f32(uint32_t h) {
    uint32_t u = h << 16;
    return __builtin_bit_cast(float, u);
}

// async global->LDS, 16B per lane. LDS dest = wave-uniform base + lane*16;
// global source address is per-lane (gather) — used for swizzled staging.
__device__ __forceinline__ void gload_lds16(const uint16_t* g, uint16_t* l) {
    __builtin_amdgcn_global_load_lds(
        (const __attribute__((address_space(1))) uint32_t*)g,
        (__attribute__((address_space(3))) uint32_t*)l, 16, 0, 0);
}

// ---------------- elementwise f32 -> bf16 ----------------
__global__ void cvt_f32_bf16(const float* __restrict__ in, uint16_t* __restrict__ out, int n) {
    int i = (blockIdx.x * blockDim.x + threadIdx.x) * 4;
    if (i + 3 < n) {
        float4 f = *reinterpret_cast<const float4*>(in + i);
        ushort4 o;
        o.x = f32_to_bf16(f.x);
        o.y = f32_to_bf16(f.y);
        o.z = f32_to_bf16(f.z);
        o.w = f32_to_bf16(f.w);
        *reinterpret_cast<ushort4*>(out + i) = o;
    }
}

// ---------------- transpose + cast: in [R][Cc] f32 -> out [Cc][R] bf16 ----------------
__global__ __launch_bounds__(256) void transpose_cvt(const float* __restrict__ in,
                                                     uint16_t* __restrict__ out,
                                                     int R, int Cc) {
    __shared__ uint16_t tile[64][65];
    int c0 = blockIdx.x * 64;
    int r0 = blockIdx.y * 64;
    int tc = threadIdx.x & 63;
    int t4 = threadIdx.x >> 6;  // 0..3
    for (int rr = t4; rr < 64; rr += 4) {
        tile[rr][tc] = f32_to_bf16(in[(size_t)(r0 + rr) * Cc + c0 + tc]);
    }
    __syncthreads();
    int wr = threadIdx.x & 63;
    for (int cc = t4; cc < 64; cc += 4) {
        out[(size_t)(c0 + cc) * R + r0 + wr] = tile[wr][cc];
    }
}

// ====== 256x256 bf16 MFMA GEMM: half-unit LDS ring, 2-cluster/3-barrier tile ======
// C[M][N] = A[M][K] * Bt[N][K]^T. 512 thr = 8 waves (2M x 4N); wave tile 128x64;
// BK=64; LDS ring of 4 half-unit slots per operand (even tiles slots 0/1, odd 2/3);
// tile t stages tile t+2's units into the slots it is reading (WAR-safe, see below).
// ROUND-6 CHANGE: collapse 4 quadrant-phases (8 barriers + 4 lgkmcnt(0) + 4
// uncovered read windows = ~2500 cyc/tile overhead; R1/R3/R4 all pinned at
// ~4990 cyc/tile vs ~2480 cyc MFMA content) into 2 MFMA clusters with barriers
// ONLY at the true cross-wave hazard points:
//   tile top: read ALL B frags (8 ds_read_b128) + A0-3 (8)
//   lgkm(8)  -> this wave's B reads landed (in regs; LDS B slot now dead to us)
//   BARRIER1 -> all waves' B reads done => stB(t+2) may overwrite B slots
//   lgkm(0)  -> A0-3 landed; 32 MFMA (mi0-3 x ni0-3 x k0,k1; 16 indep accs)
//   reload A4-7 into the SAME aA regs (register WAR sequences issue; short tail)
//   lgkm(0); BARRIER2 -> all waves' A reads done => stA(t+2) may overwrite
//   32 MFMA (mi4-7); vmcnt(8) -> t+1's units (staged at t-1) retired
//   BARRIER3 -> cross-wave visibility of t+1's slots.
// Fragment footprint = aA(32)+bB(32) = 64 VGPR sustained (R5's 96-VGPR
// phase-ahead variant spilled to scratch: WRITE_SIZE 51->247 MB. Never again.)
// vmcnt ring: at end of T, outstanding = T-1's 8 + T's 8 -> vmcnt(8) retires
// T-1's (which staged T+1). Edges: T+2>=nt -> no stage; T+1<nt -> vmcnt(0).
// XCD mapping: rectangular per-XCD tiling (R4; FETCH 176->90 MB verified).
// LDS swizzle: 16B-block c' = c ^ (row&7) via pre-swizzled global source.
// MODE 0: f32 out. MODE 2: QKV split — Q/K cols -> packed bf16 [M][2*CDIM],
// V cols -> transposed bf16 Vt[(b*16+h)*128+d][t].

#define RD8(P, OFF) (*reinterpret_cast<const bf16x8*>((P) + (OFF)))

#define RDA(DST, P, MB)                                         \
    _Pragma("unroll") for (int mi = 0; mi < 4; mi++) {          \
        DST[mi][0] = RD8(P, rdAo + ((MB) + mi) * 1024 + kblk0); \
        DST[mi][1] = RD8(P, rdAo + ((MB) + mi) * 1024 + kblk1); \
    }

#define RDB4(DST, P)                                        \
    _Pragma("unroll") for (int ni = 0; ni < 4; ni++) {      \
        DST[ni][0] = RD8(P, rdBo + ni * 1024 + kblk0);      \
        DST[ni][1] = RD8(P, rdBo + ni * 1024 + kblk1);      \
    }

// 32 MFMA: k outer so each acc's two updates are 16 instructions apart.
#define MFMA32(MB)                                                    \
    _Pragma("unroll") for (int kk = 0; kk < 2; kk++)                  \
    _Pragma("unroll") for (int mi = 0; mi < 4; mi++)                  \
    _Pragma("unroll") for (int ni = 0; ni < 4; ni++)                  \
        acc[(MB) + mi][ni] = __builtin_amdgcn_mfma_f32_16x16x32_bf16( \
            aA[mi][kk], bB[ni][kk], acc[(MB) + mi][ni], 0, 0, 0);

#define TILE(S, T)                                           \
    {                                                        \
        const int k0 = (T) * 64;                             \
        const uint16_t* pA = As + ((S) + wrow) * 8192;       \
        const uint16_t* pB = Bs + ((S) + bsel) * 8192;       \
        RDB4(bB, pB)                                         \
        RDA(aA, pA, 0)                                       \
        asm volatile("s_waitcnt lgkmcnt(8)" ::: "memory");   \
        __builtin_amdgcn_s_barrier(); /* B reads done */     \
        if ((T) + 2 < nt) {                                  \
            stB((S), 0, k0 + 128);                           \
            stB((S), 1, k0 + 128);                           \
        }                                                    \
        asm volatile("s_waitcnt lgkmcnt(0)" ::: "memory");   \
        __builtin_amdgcn_sched_barrier(0);                   \
        __builtin_amdgcn_s_setprio(1);                       \
        MFMA32(0)                                            \
        __builtin_amdgcn_s_setprio(0);                       \
        RDA(aA, pA, 4)                                       \
        asm volatile("s_waitcnt lgkmcnt(0)" ::: "memory");   \
        __builtin_amdgcn_s_barrier(); /* A reads done */     \
        if ((T) + 2 < nt) {                                  \
            stA((S), 0, k0 + 128);                           \
            stA((S), 1, k0 + 128);                           \
        }                                                    \
        __builtin_amdgcn_sched_barrier(0);                   \
        __builtin_amdgcn_s_setprio(1);                       \
        MFMA32(4)                                            \
        __builtin_amdgcn_s_setprio(0);                       \
        if ((T) + 2 < nt) {                                  \
            asm volatile("s_waitcnt vmcnt(8)" ::: "memory"); \
        } else if ((T) + 1 < nt) {                           \
            asm volatile("s_waitcnt vmcnt(0)" ::: "memory"); \
        }                                                    \
        __builtin_amdgcn_s_barrier(); /* t+1 visible */      \
        __builtin_amdgcn_sched_barrier(0);                   \
    }

template <int MODE>
__global__ __launch_bounds__(512, 2) void gemm_bf16_256(const uint16_t* __restrict__ A,
                                                        const uint16_t* __restrict__ Bt,
                                                        void* __restrict__ Cp,
                                                        uint16_t* __restrict__ vt,
                                                        int M, int N, int K, int xm) {
    __shared__ __align__(16) uint16_t lds[65536];  // 128 KiB
    uint16_t* const As = lds;          // 4 ring slots x 8192 elems (128 rows x 64 K)
    uint16_t* const Bs = lds + 32768;  // 4 ring slots

    const int tid = threadIdx.x;
    const int wave = tid >> 6;
    const int lane = tid & 63;
    const int l15 = lane & 15;
    const int quad = lane >> 4;
    const int wrow = wave >> 2;  // 0..1 -> A half
    const int wcol = wave & 3;   // 0..3
    const int bsel = wcol >> 1;  // B half

    // rectangular XCD mapping (bijective; requires xm|gm and (8/xm)|gn).
    const int gm = gridDim.y, gn = gridDim.x;
    const int flat = blockIdx.y * gn + blockIdx.x;
    const int xcd = flat & 7;
    const int j = flat >> 3;  // 0 .. gm*gn/8 - 1
    const int xn = 8 / xm;
    const int RM = gm / xm;  // rect height (m-blocks)
    const int RN = gn / xn;  // rect width (n-blocks)
    const int m_blk = (xcd / xn) * RM + (j % RM);
    const int n_blk = (xcd % xn) * RN + (j / RM);
    const int m0 = m_blk * 256;
    const int n0 = n_blk * 256;

    // staging: lane -> row (lane>>3) within 8-row slab, source 16B-block
    // (lane&7) ^ (lane>>3) so that LDS (r, c') holds global block c' ^ (r&7).
    const int srow = wave * 8 + (lane >> 3);
    const int scol = ((lane & 7) ^ (lane >> 3)) * 8;
    const uint16_t* Ag = A + (size_t)(m0 + srow) * K + scol;
    const uint16_t* Bg = Bt + (size_t)(n0 + srow) * K + scol;
    const int ldsoff = wave * 512;

    // frag-read constants within a half-unit (row&7 == l15&7 for all frag rows)
    const int rdAo = l15 * 64;
    const int rdBo = ((wcol & 1) * 64 + l15) * 64;
    const int kblk0 = (quad ^ (l15 & 7)) * 8;
    const int kblk1 = ((4 + quad) ^ (l15 & 7)) * 8;

    const int nt = K >> 6;
    f32x4 acc[8][4] = {};
    bf16x8 aA[4][2], bB[4][2];

    auto stA = [&](int sb, int h, int kk) {
        const uint16_t* s = Ag + (size_t)(h * 128) * K + kk;
        uint16_t* d = As + (sb + h) * 8192 + ldsoff;
        gload_lds16(s, d);
        gload_lds16(s + (size_t)64 * K, d + 4096);
    };
    auto stB = [&](int sb, int h, int kk) {
        const uint16_t* s = Bg + (size_t)(h * 128) * K + kk;
        uint16_t* d = Bs + (sb + h) * 8192 + ldsoff;
        gload_lds16(s, d);
        gload_lds16(s + (size_t)64 * K, d + 4096);
    };

    // prologue: tile 0 -> slots 0/1, tile 1 -> slots 2/3 (16 loads);
    // vmcnt(8) retires tile-0 units; barrier gives cross-wave visibility.
    stB(0, 0, 0);
    stB(0, 1, 0);
    stA(0, 0, 0);
    stA(0, 1, 0);
    stB(2, 0, 64);
    stB(2, 1, 64);
    stA(2, 0, 64);
    stA(2, 1, 64);
    asm volatile("s_waitcnt vmcnt(8)" ::: "memory");
    __builtin_amdgcn_s_barrier();
    __builtin_amdgcn_sched_barrier(0);

    for (int t = 0; t < nt; t += 2) {
        TILE(0, t)
        TILE(2, t + 1)
    }

    const bool vmode = (MODE == 2) && (n0 >= 2 * CDIM);  // block-uniform
#pragma unroll
    for (int mi = 0; mi < 8; mi++)
#pragma unroll
        for (int ni = 0; ni < 4; ni++) {
            if (vmode) {
                // V cols: write transposed into Vt[(b*16+h)*128+d][t].
                int col = n0 + wcol * 64 + ni * 16 + l15;
                int vcol = col - 2 * CDIM;
                int hh = vcol >> 7, d = vcol & 127;
                int rowm = m0 + wrow * 128 + mi * 16 + quad * 4;
                int bb = rowm >> 11, tt = rowm & 2047;
                uint32_t lo = (uint32_t)f32_to_bf16(acc[mi][ni][0]) |
                              ((uint32_t)f32_to_bf16(acc[mi][ni][1]) << 16);
                uint32_t hi = (uint32_t)f32_to_bf16(acc[mi][ni][2]) |
                              ((uint32_t)f32_to_bf16(acc[mi][ni][3]) << 16);
                *reinterpret_cast<uint2*>(
                    vt + ((size_t)((bb * HDIM + hh) * DHEAD + d)) * TLEN + tt) =
                    make_uint2(lo, hi);
            } else {
#pragma unroll
                for (int r = 0; r < 4; r++) {
                    int row = m0 + wrow * 128 + mi * 16 + quad * 4 + r;
                    int col = n0 + wcol * 64 + ni * 16 + l15;
                    float v = acc[mi][ni][r];
                    if (MODE == 2)
                        ((uint16_t*)Cp)[(size_t)row * (2 * CDIM) + col] = f32_to_bf16(v);
                    else if (MODE == 1)
                        ((uint16_t*)Cp)[(size_t)row * N + col] = f32_to_bf16(v);
                    else
                        ((float*)Cp)[(size_t)row * N + col] = v;
                }
            }
        }
}

// ---------------- MFMA flash attention v3 (QROW = 2*CDIM) ----------------
#define ATT_C1 0.12751743f
#define ATT_C2 17.3123405f

__global__ __launch_bounds__(256) void attn_mfma3(const uint16_t* __restrict__ qkv,
                                                  const uint16_t* __restrict__ vtg,
                                                  uint16_t* __restrict__ y) {
    __shared__ __align__(16) uint16_t Ks[64 * 128];    // swizzled: c' = c ^ (key&15)
    __shared__ __align__(16) uint16_t Vts[128 * 64];   // swizzled: c' = c ^ (d&7)
    __shared__ __align__(16) uint16_t Ps[4][32 * 72];  // per-wave P [q][key]

    const int tid = threadIdx.x;
    const int wave = tid >> 6;
    const int lane = tid & 63;
    const int l15 = lane & 15;
    const int quad = lane >> 4;
    const int h = blockIdx.y;
    const int b = blockIdx.z;
    const int qblk = (int)gridDim.x - 1 - (int)blockIdx.x;
    const int qbase = qblk * 128 + wave * 32;
    const int kmax = qbase + 31;

    const uint16_t* kg = qkv + (size_t)b * TLEN * QROW + CDIM + h * DHEAD;
    const uint16_t* vg = vtg + (size_t)(b * HDIM + h) * DHEAD * TLEN;
    uint16_t* PsW = Ps[wave];

    int koff[4], voff[4];
#pragma unroll
    for (int i = 0; i < 4; i++) {
        int Lb = (wave * 4 + i) * 64 + lane;
        int key = Lb >> 4;
        int ck = (Lb & 15) ^ (key & 15);
        koff[i] = key * (int)QROW + ck * 8;
        int d = Lb >> 3;
        int cv = (Lb & 7) ^ (d & 7);
        voff[i] = d * TLEN + cv * 8;
    }

    bf16x8 qfrag[2][4];
#pragma unroll
    for (int m = 0; m < 2; m++) {
        const uint16_t* qp =
            qkv + (size_t)(b * TLEN + qbase + m * 16 + l15) * QROW + h * DHEAD + quad * 8;
#pragma unroll
        for (int kc = 0; kc < 4; kc++)
            qfrag[m][kc] = *reinterpret_cast<const bf16x8*>(qp + kc * 32);
    }

    f32x4 oacc[2][8] = {};
    float psum[2] = {0.f, 0.f};

    const int diagT = qblk * 2 + (wave >> 1);
    const int ntiles = qblk * 2 + 2;

    for (int t = 0; t < ntiles; t++) {
        const int j0 = t * 64;
        if (t > 0) __syncthreads();
        {
            const uint16_t* kj = kg + (size_t)j0 * QROW;
            const uint16_t* vj = vg + j0;
#pragma unroll
            for (int i = 0; i < 4; i++) {
                gload_lds16(kj + koff[i], Ks + (wave * 4 + i) * 512);
                gload_lds16(vj + voff[i], Vts + (wave * 4 + i) * 512);
            }
        }
        __syncthreads();
        if (t > diagT) continue;

        const bool masked = (t == diagT);
        const int n0max = masked ? ((kmax - j0) >> 4) : 3;

        f32x4 st[4][2];
#pragma unroll
        for (int n0 = 0; n0 < 4; n0++) {
            if (masked && n0 > n0max) continue;
            bf16x8 kf[4];
#pragma unroll
            for (int kc = 0; kc < 4; kc++) {
                int cpr = (kc * 4 + quad) ^ l15;
                kf[kc] = *reinterpret_cast<const bf16x8*>(
                    Ks + (n0 * 16 + l15) * 128 + cpr * 8);
            }
#pragma unroll
            for (int m = 0; m < 2; m++) {
                f32x4 acc = {};
#pragma unroll
                for (int kc = 0; kc < 4; kc++)
                    acc = __builtin_amdgcn_mfma_f32_16x16x32_bf16(
                        kf[kc], qfrag[m][kc], acc, 0, 0, 0);
                st[n0][m] = acc;
            }
        }

#pragma unroll
        for (int n0 = 0; n0 < 4; n0++) {
            if (masked && n0 > n0max) continue;
#pragma unroll
            for (int m = 0; m < 2; m++) {
                uint32_t pk0, pk1;
                float pv[4];
#pragma unroll
                for (int r = 0; r < 4; r++) {
                    float p = exp2f(st[n0][m][r] * ATT_C1 - ATT_C2);
                    if (masked) {
                        int key = j0 + n0 * 16 + quad * 4 + r;
                        int q = qbase + m * 16 + l15;
                        if (key > q) p = 0.f;
                    }
                    uint32_t pb = f32_to_bf16(p);
                    pv[r] = bf16_to_f32(pb);
                    if (r == 0) pk0 = pb;
                    else if (r == 1) pk0 |= pb << 16;
                    else if (r == 2) pk1 = pb;
                    else pk1 |= pb << 16;
                }
                psum[m] += (pv[0] + pv[1]) + (pv[2] + pv[3]);
                *reinterpret_cast<uint2*>(PsW + (m * 16 + l15) * 72 + n0 * 16 + quad * 4) =
                    make_uint2(pk0, pk1);
            }
        }

        const int kcend = masked ? (((kmax - j0) >> 5) + 1) : 2;
#pragma unroll
        for (int kc = 0; kc < 2; kc++) {
            if (kc >= kcend) continue;
            bf16x8 pf[2];
#pragma unroll
            for (int m = 0; m < 2; m++)
                pf[m] = *reinterpret_cast<const bf16x8*>(
                    PsW + (m * 16 + l15) * 72 + kc * 32 + quad * 8);
#pragma unroll
            for (int n0 = 0; n0 < 8; n0++) {
                int cpr = (kc * 4 + quad) ^ (l15 & 7);
                bf16x8 vf = *reinterpret_cast<const bf16x8*>(
                    Vts + (n0 * 16 + l15) * 64 + cpr * 8);
#pragma unroll
                for (int m = 0; m < 2; m++)
                    oacc[m][n0] = __builtin_amdgcn_mfma_f32_16x16x32_bf16(
                        pf[m], vf, oacc[m][n0], 0, 0, 0);
            }
        }
    }

#pragma unroll
    for (int m = 0; m < 2; m++) {
        float s = psum[m];
        s += __shfl_xor(s, 16);
        s += __shfl_xor(s, 32);
        psum[m] = 1.0f / s;
    }
    uint16_t* ybase = y + (size_t)(b * TLEN + qbase) * CDIM + h * DHEAD;
#pragma unroll
    for (int m = 0; m < 2; m++)
#pragma unroll
        for (int r = 0; r < 4; r++) {
            float inv = __shfl(psum[m], quad * 4 + r);
#pragma unroll
            for (int n0 = 0; n0 < 8; n0++)
                ybase[(size_t)(m * 16 + quad * 4 + r) * CDIM + n0 * 16 + l15] =
                    f32_to_bf16(oacc[m][n0][r] * inv);
        }
}

extern "C" void kernel_launch(void* const* d_in, const int* in_sizes, int n_in,
                              void* d_out, int out_size, void* d_ws, size_t ws_size,
                              hipStream_t stream) {
    const float* x = (const float*)d_in[0];       // [2,2048,2048]
    const float* w_attn = (const float*)d_in[1];  // [2048, 6144]
    const float* w_proj = (const float*)d_in[2];  // [2048, 2048]
    float* out = (float*)d_out;                   // [2,2048,2048]

    const int M = BDIM * TLEN;  // 4096
    const int K = CDIM;         // 2048
    const int N3 = 3 * CDIM;    // 6144

    char* ws = (char*)d_ws;
    uint16_t* xb = (uint16_t*)(ws);              // 16 MB: x bf16
    uint16_t* waT = (uint16_t*)(ws + 16777216);  // 24 MB: w_attn^T bf16 [6144][2048]
    uint16_t* wpT = (uint16_t*)(ws + 41943040);  // 8 MB: w_proj^T bf16 [2048][2048]
    uint16_t* qkp = (uint16_t*)(ws + 50331648);  // 32 MB: packed Q/K bf16 [4096][4096]
    uint16_t* vtb = (uint16_t*)(ws + 83886080);  // 16 MB: Vt bf16 [(b*16+h)*128+d][2048]
    uint16_t* yb = (uint16_t*)(ws + 100663296);  // 16 MB: y bf16 [4096][2048]

    // 1. cast x to bf16
    cvt_f32_bf16<<<(M * K / 4 + 255) / 256, 256, 0, stream>>>(x, xb, M * K);
    // 2. transpose+cast weights
    transpose_cvt<<<dim3(N3 / 64, K / 64), 256, 0, stream>>>(w_attn, waT, K, N3);
    transpose_cvt<<<dim3(K / 64, K / 64), 256, 0, stream>>>(w_proj, wpT, K, K);
    // 3. qkv = x @ w_attn; Q/K cols -> qkp (stride 4096), V cols -> vtb transposed
    //    grid 24x16 -> XCD rect 8m x 6n (xm=2)
    gemm_bf16_256<2><<<dim3(N3 / 256, M / 256), 512, 0, stream>>>(xb, waT, (void*)qkp, vtb, M, N3, K, 2);
    // 4. attention -> y bf16 [4096][2048]
    attn_mfma3<<<dim3(TLEN / 128, HDIM, BDIM), 256, 0, stream>>>(qkp, vtb, yb);
    // 5. out = y @ w_proj   fp32 [4096][2048]
    //    grid 8x16 -> XCD rect 4m x 4n (xm=4)
    gemm_bf16_256<0><<<dim3(K / 256, M / 256), 512, 0, stream>>>(yb, wpT, (void*)out, nullptr, M, K, K, 4);
}